// Round 1
// baseline (2895.843 us; speedup 1.0000x reference)
//
#include <hip/hip_runtime.h>

// MetaTransformer: L=4 layers, H=8 heads, D=256, B=8, N1=2048 tokens.
// Algebraic collapse: per layer,
//   G[b]   = Z[b,:2047,:256]^T @ Z[b,:2047,:257]          (256 x 257)
//   M[b]   = (1/2047) * sum_j Q_j @ (G[b] @ Pfull_j^T)    (256 x 257)
//   Z[b]  += Z[b,:,:256] @ M[b]                           (2048 x 257)
// where (G @ Pfull^T)[:, c<256] = G[:,:256] @ P^T, col 256 = G[:,256].

#define NL   4
#define NH   8
#define DD   256
#define NCH  257
#define NTOK 2048
#define NVAL 2047
#define NB   8

// ---------------- Kernel A: Gram  G[b][k][c] = sum_{m<2047} Z[b][m][k]*Z[b][m][c]
__global__ __launch_bounds__(256) void gram_kernel(const float* __restrict__ Z,
                                                   float* __restrict__ G) {
  __shared__ float As[32][64];   // [mm][kk]
  __shared__ float Bs[32][65];   // [mm][cc]
  const int c0 = blockIdx.x * 64;
  const int k0 = blockIdx.y * 64;
  const int b  = blockIdx.z;
  const int tid = threadIdx.x;
  const int tx = tid & 15, ty = tid >> 4;
  const float* Zb = Z + (size_t)b * NTOK * NCH;
  float acc[4][4] = {};
  for (int m0 = 0; m0 < NVAL; m0 += 32) {
    #pragma unroll
    for (int l = 0; l < 8; ++l) {
      int e = tid + l * 256;
      int mm = e >> 6, kk = e & 63;
      int m = m0 + mm;
      As[mm][kk] = (m < NVAL) ? Zb[(size_t)m * NCH + (k0 + kk)] : 0.f;
    }
    #pragma unroll
    for (int l = 0; l < 8; ++l) {
      int e = tid + l * 256;
      int mm = e >> 6, cc = e & 63;
      int m = m0 + mm, c = c0 + cc;
      Bs[mm][cc] = (m < NVAL && c < NCH) ? Zb[(size_t)m * NCH + c] : 0.f;
    }
    __syncthreads();
    #pragma unroll
    for (int mm = 0; mm < 32; ++mm) {
      float a[4], bb[4];
      #pragma unroll
      for (int i = 0; i < 4; ++i) a[i] = As[mm][ty * 4 + i];
      #pragma unroll
      for (int j = 0; j < 4; ++j) bb[j] = Bs[mm][tx * 4 + j];
      #pragma unroll
      for (int i = 0; i < 4; ++i)
        #pragma unroll
        for (int j = 0; j < 4; ++j) acc[i][j] += a[i] * bb[j];
    }
    __syncthreads();
  }
  float* Gb = G + (size_t)b * DD * NCH;
  #pragma unroll
  for (int i = 0; i < 4; ++i) {
    int k = k0 + ty * 4 + i;
    #pragma unroll
    for (int j = 0; j < 4; ++j) {
      int c = c0 + tx * 4 + j;
      if (c < NCH) Gb[(size_t)k * NCH + c] = acc[i][j];
    }
  }
}

// ---------------- Kernel B1: U[b,jj] = G[b] @ Pfull_j^T
// U[k][c<256] = sum_{t<256} G[k][t]*P[c][t];  U[k][256] = G[k][256]
__global__ __launch_bounds__(256) void pmul_kernel(const float* __restrict__ G,
                                                   const float* __restrict__ allparam,
                                                   float* __restrict__ U,
                                                   int layer, int j0, int JB) {
  __shared__ float As[64][33];   // [kk][tt]
  __shared__ float Bs[64][33];   // [cc][tt]
  const int c0 = blockIdx.x * 64;
  const int k0 = blockIdx.y * 64;
  const int b  = blockIdx.z / JB;
  const int jj = blockIdx.z % JB;
  const int j  = j0 + jj;
  const int tid = threadIdx.x;
  const int tx = tid & 15, ty = tid >> 4;
  const float* P  = allparam + ((size_t)((layer * NH + j) * 2 + 0)) * DD * DD;
  const float* Gb = G + (size_t)b * DD * NCH;
  float acc[4][4] = {};
  for (int t0 = 0; t0 < DD; t0 += 32) {
    #pragma unroll
    for (int l = 0; l < 8; ++l) {
      int e = tid + l * 256;
      int kk = e >> 5, tt = e & 31;
      As[kk][tt] = Gb[(size_t)(k0 + kk) * NCH + (t0 + tt)];
    }
    #pragma unroll
    for (int l = 0; l < 8; ++l) {
      int e = tid + l * 256;
      int cc = e >> 5, tt = e & 31;
      int c = c0 + cc;
      Bs[cc][tt] = (c < DD) ? P[(size_t)c * DD + (t0 + tt)] : 0.f;
    }
    __syncthreads();
    #pragma unroll
    for (int tt = 0; tt < 32; ++tt) {
      float a[4], bb[4];
      #pragma unroll
      for (int i = 0; i < 4; ++i) a[i] = As[ty * 4 + i][tt];
      #pragma unroll
      for (int j2 = 0; j2 < 4; ++j2) bb[j2] = Bs[tx * 4 + j2][tt];
      #pragma unroll
      for (int i = 0; i < 4; ++i)
        #pragma unroll
        for (int j2 = 0; j2 < 4; ++j2) acc[i][j2] += a[i] * bb[j2];
    }
    __syncthreads();
  }
  float* Us = U + ((size_t)(b * JB + jj)) * DD * NCH;
  #pragma unroll
  for (int i = 0; i < 4; ++i) {
    int k = k0 + ty * 4 + i;
    #pragma unroll
    for (int j2 = 0; j2 < 4; ++j2) {
      int c = c0 + tx * 4 + j2;
      if (c < DD)       Us[(size_t)k * NCH + c] = acc[i][j2];
      else if (c == DD) Us[(size_t)k * NCH + c] = Gb[(size_t)k * NCH + DD];
    }
  }
}

// ---------------- Kernel B2: M[b] (+)= (1/N) * sum_jj Q_{j0+jj} @ U[b,jj]
__global__ __launch_bounds__(256) void qmul_kernel(const float* __restrict__ U,
                                                   const float* __restrict__ allparam,
                                                   float* __restrict__ M,
                                                   int layer, int j0, int jcount, int JB,
                                                   int accumulate) {
  __shared__ float As[64][33];   // [kk][tt]
  __shared__ float Bs[32][65];   // [tt][cc]
  const int c0 = blockIdx.x * 64;
  const int k0 = blockIdx.y * 64;
  const int b  = blockIdx.z;
  const int tid = threadIdx.x;
  const int tx = tid & 15, ty = tid >> 4;
  const float invN = 1.0f / (float)NVAL;
  float acc[4][4] = {};
  for (int jj = 0; jj < jcount; ++jj) {
    const float* Q  = allparam + ((size_t)((layer * NH + (j0 + jj)) * 2 + 1)) * DD * DD;
    const float* Ub = U + ((size_t)(b * JB + jj)) * DD * NCH;
    for (int t0 = 0; t0 < DD; t0 += 32) {
      #pragma unroll
      for (int l = 0; l < 8; ++l) {
        int e = tid + l * 256;
        int kk = e >> 5, tt = e & 31;
        As[kk][tt] = Q[(size_t)(k0 + kk) * DD + (t0 + tt)];
      }
      #pragma unroll
      for (int l = 0; l < 8; ++l) {
        int e = tid + l * 256;
        int tt = e >> 6, cc = e & 63;
        int c = c0 + cc;
        Bs[tt][cc] = (c < NCH) ? Ub[(size_t)(t0 + tt) * NCH + c] : 0.f;
      }
      __syncthreads();
      #pragma unroll
      for (int tt = 0; tt < 32; ++tt) {
        float a[4], bb[4];
        #pragma unroll
        for (int i = 0; i < 4; ++i) a[i] = As[ty * 4 + i][tt];
        #pragma unroll
        for (int j2 = 0; j2 < 4; ++j2) bb[j2] = Bs[tt][tx * 4 + j2];
        #pragma unroll
        for (int i = 0; i < 4; ++i)
          #pragma unroll
          for (int j2 = 0; j2 < 4; ++j2) acc[i][j2] += a[i] * bb[j2];
      }
      __syncthreads();
    }
  }
  #pragma unroll
  for (int i = 0; i < 4; ++i) {
    int k = k0 + ty * 4 + i;
    #pragma unroll
    for (int j2 = 0; j2 < 4; ++j2) {
      int c = c0 + tx * 4 + j2;
      if (c < NCH) {
        size_t idx = ((size_t)b * DD + k) * NCH + c;
        float v = invN * acc[i][j2];
        M[idx] = accumulate ? (M[idx] + v) : v;
      }
    }
  }
}

// ---------------- Kernel C: Z[b][n][c] += sum_{k<256} Z[b][n][k] * M[b][k][c]  (row-local, in-place safe)
__global__ __launch_bounds__(256) void apply_kernel(float* __restrict__ Z,
                                                    const float* __restrict__ M) {
  __shared__ float Zs[8][256];
  const int b  = blockIdx.y;
  const int n0 = blockIdx.x * 8;
  float* Zb = Z + (size_t)b * NTOK * NCH;
  const float* Mb = M + (size_t)b * DD * NCH;
  const int tid = threadIdx.x;
  #pragma unroll
  for (int l = 0; l < 8; ++l) {
    int e = tid + l * 256;
    int r = e >> 8, k = e & 255;
    Zs[r][k] = Zb[(size_t)(n0 + r) * NCH + k];
  }
  __syncthreads();
  const int r = tid >> 5;
  const int cbase = tid & 31;
  float acc[9] = {};
  #pragma unroll 4
  for (int k = 0; k < 256; ++k) {
    float z = Zs[r][k];
    const float* Mrow = Mb + (size_t)k * NCH;
    #pragma unroll
    for (int ii = 0; ii < 8; ++ii) acc[ii] += z * Mrow[cbase + ii * 32];
    if (cbase == 0) acc[8] += z * Mrow[256];
  }
  #pragma unroll
  for (int ii = 0; ii < 8; ++ii)
    Zb[(size_t)(n0 + r) * NCH + cbase + ii * 32] += acc[ii];
  if (cbase == 0) Zb[(size_t)(n0 + r) * NCH + 256] += acc[8];
}

extern "C" void kernel_launch(void* const* d_in, const int* in_sizes, int n_in,
                              void* d_out, int out_size, void* d_ws, size_t ws_size,
                              hipStream_t stream) {
  const float* Zin      = (const float*)d_in[0];
  const float* allparam = (const float*)d_in[1];
  float* Z = (float*)d_out;

  const size_t zbytes = (size_t)NB * NTOK * NCH * sizeof(float);
  hipMemcpyAsync(Z, Zin, zbytes, hipMemcpyDeviceToDevice, stream);

  const size_t Gn = (size_t)NB * DD * NCH;   // floats per {G,M} buffer (and per U head-slot set)
  float* ws   = (float*)d_ws;
  float* Gbuf = ws;
  float* Mbuf = ws + Gn;
  float* Ubuf = ws + 2 * Gn;
  // U needs NB*JB*DD*NCH = JB*Gn floats. Prefer all 8 heads at once; fall back to 1.
  const int JB = (ws_size >= (size_t)(2 + 8) * Gn * sizeof(float)) ? 8 : 1;

  dim3 blk(256);
  for (int layer = 0; layer < NL; ++layer) {
    gram_kernel<<<dim3(5, 4, NB), blk, 0, stream>>>(Z, Gbuf);
    for (int j0 = 0; j0 < NH; j0 += JB) {
      pmul_kernel<<<dim3(5, 4, NB * JB), blk, 0, stream>>>(Gbuf, allparam, Ubuf, layer, j0, JB);
      qmul_kernel<<<dim3(5, 4, NB), blk, 0, stream>>>(Ubuf, allparam, Mbuf, layer, j0, JB, JB,
                                                      (j0 == 0) ? 0 : 1);
    }
    apply_kernel<<<dim3(NTOK / 8, NB), blk, 0, stream>>>(Z, Mbuf);
  }
}

// Round 2
// 387.042 us; speedup vs baseline: 7.4820x; 7.4820x over previous
//
#include <hip/hip_runtime.h>

// MetaTransformer collapse: per layer,
//   G[b]  = Zx[b,:2047]^T Zx[b,:2047]        (256x256, symmetric)  gcol = Zx^T zlab
//   M[b]  = (1/N) sum_j Q_j G P_j^T          (256x256)             mcol = (1/N) Qsum gcol
//   Z[b] += Zx[b] M[b]  (+ col-256 GEMV with mcol)
// All MFMA GEMMs in A*B^T form: D[r][c] = sum_k A'[r][k]*B'[c][k], both row-major bf16.

#define NL   4
#define NH   8
#define DD   256
#define NCH  257
#define NTOK 2048
#define NVAL 2047
#define NB   8

typedef short  short8v __attribute__((ext_vector_type(8)));
typedef short  short4v __attribute__((ext_vector_type(4)));
typedef float  f32x4   __attribute__((ext_vector_type(4)));

__device__ __forceinline__ unsigned short f2b(float x) {
  union { float f; unsigned u; } v; v.f = x;
  unsigned u = v.u + 0x7fffu + ((v.u >> 16) & 1u);
  return (unsigned short)(u >> 16);
}
__device__ __forceinline__ float b2f(short s) {
  union { unsigned u; float f; } v; v.u = ((unsigned)(unsigned short)s) << 16;
  return v.f;
}

// ---- shared MFMA tile: 4 waves, 128x128 wg tile, 64x64 per wave, K step 32.
__device__ __forceinline__ void mm_tile(const short* __restrict__ A, const short* __restrict__ B,
                                        int lda, int ldb, int ar, int bc, int k0, int k1,
                                        int lane, f32x4 acc[4][4]) {
  #pragma unroll 2
  for (int kk = k0; kk < k1; kk += 32) {
    const int kc = kk + ((lane >> 4) << 3);
    short8v av[4], bv[4];
    #pragma unroll
    for (int f = 0; f < 4; ++f)
      av[f] = *(const short8v*)(A + (size_t)(ar + f * 16 + (lane & 15)) * lda + kc);
    #pragma unroll
    for (int g = 0; g < 4; ++g)
      bv[g] = *(const short8v*)(B + (size_t)(bc + g * 16 + (lane & 15)) * ldb + kc);
    #pragma unroll
    for (int f = 0; f < 4; ++f)
      #pragma unroll
      for (int g = 0; g < 4; ++g)
        acc[f][g] = __builtin_amdgcn_mfma_f32_16x16x32_bf16(av[f], bv[g], acc[f][g], 0, 0, 0);
  }
}

// ---- prep: params -> bf16 (P natural, Q natural)
__global__ __launch_bounds__(256) void k_prep_pq(const float* __restrict__ ap,
                                                 short* __restrict__ Pbf, short* __restrict__ Qbf) {
  int gid = blockIdx.x * 256 + threadIdx.x;          // 4*8*16384 = 524288
  int lj = gid >> 14, rc4 = gid & 16383;
  const f32x4* src = (const f32x4*)ap;
  f32x4 pv = src[(size_t)(lj * 2 + 0) * 16384 + rc4];
  f32x4 qv = src[(size_t)(lj * 2 + 1) * 16384 + rc4];
  short4v p, q;
  #pragma unroll
  for (int i = 0; i < 4; ++i) { p[i] = (short)f2b(pv[i]); q[i] = (short)f2b(qv[i]); }
  ((short4v*)Pbf)[(size_t)lj * 16384 + rc4] = p;
  ((short4v*)Qbf)[(size_t)lj * 16384 + rc4] = q;
}

// ---- prep: QsumT[l][t][k] = sum_j Q_j[k][t]  (fp32)
__global__ __launch_bounds__(256) void k_qsumt(const float* __restrict__ ap, float* __restrict__ QsumT) {
  __shared__ float lds[64][65];
  const int l = blockIdx.y;
  const int k0 = (blockIdx.x >> 2) * 64, t0 = (blockIdx.x & 3) * 64;
  const int tid = threadIdx.x, c = tid & 63, r = tid >> 6;
  #pragma unroll
  for (int i = 0; i < 16; ++i) {
    int k = r + i * 4;
    float s = 0.f;
    #pragma unroll
    for (int j = 0; j < 8; ++j)
      s += ap[(size_t)((l * 8 + j) * 2 + 1) * 65536 + (size_t)(k0 + k) * 256 + (t0 + c)];
    lds[k][c] = s;
  }
  __syncthreads();
  #pragma unroll
  for (int i = 0; i < 16; ++i) {
    int tl = r + i * 4;
    QsumT[(size_t)l * 65536 + (size_t)(t0 + tl) * 256 + (k0 + c)] = lds[c][tl];
  }
}

// ---- per layer: Z fp32 -> Zxt (transposed bf16, m=2047 zeroed), Zxbf (natural bf16), gcol partials
__global__ __launch_bounds__(256) void k_transpose(const float* __restrict__ Z,
                                                   short* __restrict__ Zxt, short* __restrict__ Zxbf,
                                                   float* __restrict__ gcol) {
  __shared__ float tile[64][65];
  __shared__ float zl[64];
  const int k0 = blockIdx.x * 64, m0 = blockIdx.y * 64, b = blockIdx.z;
  const int tid = threadIdx.x, c = tid & 63, r = tid >> 6;
  #pragma unroll
  for (int i = 0; i < 16; ++i) {
    int mrow = r + i * 4, m = m0 + mrow;
    float v = Z[((size_t)b * NTOK + m) * NCH + k0 + c];
    tile[mrow][c] = v;
    Zxbf[((size_t)b * NTOK + m) * DD + k0 + c] = (short)f2b(v);
  }
  if (tid < 64) {
    int m = m0 + tid;
    zl[tid] = (m == NVAL) ? 0.f : Z[((size_t)b * NTOK + m) * NCH + DD];
  }
  __syncthreads();
  #pragma unroll
  for (int i = 0; i < 16; ++i) {
    int krow = r + i * 4;
    float v = tile[c][krow];
    if (m0 + c == NVAL) v = 0.f;
    Zxt[((size_t)b * DD + k0 + krow) * NTOK + m0 + c] = (short)f2b(v);
  }
  // gcol partial: sum over this block's 64 m
  float s = 0.f;
  #pragma unroll
  for (int i = 0; i < 16; ++i) s += tile[r * 16 + i][c] * zl[r * 16 + i];
  atomicAdd(&gcol[b * 256 + k0 + c], s);
}

// ---- gram: Gacc[seg][b] += Zxt(tileR) * Zxt(tileC)^T over m-segment
__global__ __launch_bounds__(256) void k_gram(const short* __restrict__ Zxt, float* __restrict__ Gacc) {
  const int tid = threadIdx.x, lane = tid & 63, wid = tid >> 6;
  const int wr = wid >> 1, wc = wid & 1;
  const int seg = blockIdx.y, b = blockIdx.z;
  const int ar = (blockIdx.x >> 1) * 128 + wr * 64;
  const int bc = (blockIdx.x & 1) * 128 + wc * 64;
  const short* A = Zxt + (size_t)b * DD * NTOK;
  f32x4 acc[4][4];
  #pragma unroll
  for (int f = 0; f < 4; ++f) for (int g = 0; g < 4; ++g) for (int i = 0; i < 4; ++i) acc[f][g][i] = 0.f;
  mm_tile(A, A, NTOK, NTOK, ar, bc, seg * 256, seg * 256 + 256, lane, acc);
  float* out = Gacc + (size_t)(seg * 8 + b) * 65536;
  #pragma unroll
  for (int f = 0; f < 4; ++f)
    #pragma unroll
    for (int g = 0; g < 4; ++g)
      #pragma unroll
      for (int i = 0; i < 4; ++i)
        out[(size_t)(ar + f * 16 + ((lane >> 4) << 2) + i) * 256 + bc + g * 16 + (lane & 15)] = acc[f][g][i];
}

// ---- gconv: Gbf = bf16(sum_seg Gacc)
__global__ __launch_bounds__(256) void k_gconv(const float* __restrict__ Gacc, short* __restrict__ Gbf) {
  const int b = blockIdx.x >> 5, t = blockIdx.x & 31;
  const int e0 = t * 2048 + threadIdx.x * 8;
  float a[8];
  #pragma unroll
  for (int i = 0; i < 8; ++i) a[i] = 0.f;
  #pragma unroll
  for (int s = 0; s < 8; ++s) {
    const f32x4* p = (const f32x4*)(Gacc + (size_t)(s * 8 + b) * 65536 + e0);
    f32x4 x = p[0], y = p[1];
    #pragma unroll
    for (int i = 0; i < 4; ++i) { a[i] += x[i]; a[4 + i] += y[i]; }
  }
  short8v o;
  #pragma unroll
  for (int i = 0; i < 8; ++i) o[i] = (short)f2b(a[i]);
  *(short8v*)(Gbf + (size_t)b * 65536 + e0) = o;
}

// ---- pmul: Vt[b][j][c][t] = (G * P_j^T)[t][c]   (A'=G, B'=P, transposed 8B stores)
__global__ __launch_bounds__(256) void k_pmul(const short* __restrict__ Gbf, const short* __restrict__ Pbf,
                                              short* __restrict__ Vt, int layer) {
  const int tid = threadIdx.x, lane = tid & 63, wid = tid >> 6;
  const int wr = wid >> 1, wc = wid & 1;
  const int j = blockIdx.y, b = blockIdx.z;
  const int ar = (blockIdx.x >> 1) * 128 + wr * 64;   // t rows
  const int bc = (blockIdx.x & 1) * 128 + wc * 64;    // c rows
  const short* A = Gbf + (size_t)b * 65536;
  const short* B = Pbf + (size_t)(layer * 8 + j) * 65536;
  f32x4 acc[4][4];
  #pragma unroll
  for (int f = 0; f < 4; ++f) for (int g = 0; g < 4; ++g) for (int i = 0; i < 4; ++i) acc[f][g][i] = 0.f;
  mm_tile(A, B, 256, 256, ar, bc, 0, 256, lane, acc);
  short* out = Vt + (size_t)(b * 8 + j) * 65536;
  #pragma unroll
  for (int f = 0; f < 4; ++f)
    #pragma unroll
    for (int g = 0; g < 4; ++g) {
      int c = bc + g * 16 + (lane & 15);
      int t0 = ar + f * 16 + ((lane >> 4) << 2);
      short4v p;
      #pragma unroll
      for (int i = 0; i < 4; ++i) p[i] = (short)f2b(acc[f][g][i]);
      *(short4v*)(out + (size_t)c * 256 + t0) = p;
    }
}

// ---- qmul: Macc[jseg][b] = sum_{j in seg} Q_j * V'_j   (A'=Q, B'=Vt)
__global__ __launch_bounds__(256) void k_qmul(const short* __restrict__ Qbf, const short* __restrict__ Vt,
                                              float* __restrict__ Macc, int layer) {
  const int tid = threadIdx.x, lane = tid & 63, wid = tid >> 6;
  const int wr = wid >> 1, wc = wid & 1;
  const int jseg = blockIdx.y, b = blockIdx.z;
  const int ar = (blockIdx.x >> 1) * 128 + wr * 64;   // k rows
  const int bc = (blockIdx.x & 1) * 128 + wc * 64;    // c rows
  f32x4 acc[4][4];
  #pragma unroll
  for (int f = 0; f < 4; ++f) for (int g = 0; g < 4; ++g) for (int i = 0; i < 4; ++i) acc[f][g][i] = 0.f;
  for (int jj = jseg * 2; jj < jseg * 2 + 2; ++jj) {
    const short* A = Qbf + (size_t)(layer * 8 + jj) * 65536;
    const short* B = Vt + (size_t)(b * 8 + jj) * 65536;
    mm_tile(A, B, 256, 256, ar, bc, 0, 256, lane, acc);
  }
  float* out = Macc + (size_t)(jseg * 8 + b) * 65536;
  #pragma unroll
  for (int f = 0; f < 4; ++f)
    #pragma unroll
    for (int g = 0; g < 4; ++g)
      #pragma unroll
      for (int i = 0; i < 4; ++i)
        out[(size_t)(ar + f * 16 + ((lane >> 4) << 2) + i) * 256 + bc + g * 16 + (lane & 15)] = acc[f][g][i];
}

// ---- Mconv: Mt[b][c][k] = bf16(invN * sum_p Macc[p][b][k][c]); block x==16 computes mcol
__global__ __launch_bounds__(256) void k_mconv(const float* __restrict__ Macc, short* __restrict__ Mt,
                                               const float* __restrict__ QsumT, const float* __restrict__ gcol,
                                               float* __restrict__ mcol, int layer) {
  const float invN = 1.0f / (float)NVAL;
  const int b = blockIdx.y, tid = threadIdx.x;
  if (blockIdx.x == 16) {
    __shared__ float gs[256];
    gs[tid] = gcol[b * 256 + tid];
    __syncthreads();
    float s = 0.f;
    for (int t = 0; t < 256; ++t) s += QsumT[(size_t)layer * 65536 + (size_t)t * 256 + tid] * gs[t];
    mcol[b * 256 + tid] = s * invN;
    return;
  }
  __shared__ float lds[64][65];
  const int k0 = (blockIdx.x >> 2) * 64, c0 = (blockIdx.x & 3) * 64;
  const int c = tid & 63, r = tid >> 6;
  #pragma unroll
  for (int i = 0; i < 16; ++i) {
    int k = r + i * 4;
    float s = 0.f;
    #pragma unroll
    for (int p = 0; p < 4; ++p)
      s += Macc[(size_t)(p * 8 + b) * 65536 + (size_t)(k0 + k) * 256 + c0 + c];
    lds[k][c] = s * invN;
  }
  __syncthreads();
  #pragma unroll
  for (int i = 0; i < 16; ++i) {
    int cl = r + i * 4;
    Mt[(size_t)b * 65536 + (size_t)(c0 + cl) * 256 + (k0 + c)] = (short)f2b(lds[c][cl]);
  }
}

// ---- apply: Z[b][n][c] += (Zxbf * Mt^T)[n][c]; col-256 via mcol GEMV; zeroes gcol for next layer
__global__ __launch_bounds__(256) void k_apply(float* __restrict__ Z,
                                               const short* __restrict__ Zxbf, const short* __restrict__ Mt,
                                               const float* __restrict__ mcol, float* __restrict__ gcol) {
  const int tid = threadIdx.x, lane = tid & 63, wid = tid >> 6;
  const int wr = wid >> 1, wc = wid & 1;
  const int b = blockIdx.z;
  const int ar = blockIdx.y * 128 + wr * 64;          // n rows
  const int bc = blockIdx.x * 128 + wc * 64;          // c rows
  if (blockIdx.x == 0 && blockIdx.y == 0) gcol[b * 256 + tid] = 0.f;
  const short* A = Zxbf + (size_t)b * NTOK * DD;
  const short* B = Mt + (size_t)b * 65536;
  const bool gemv = (blockIdx.x == 0 && wc == 0);
  f32x4 acc[4][4];
  #pragma unroll
  for (int f = 0; f < 4; ++f) for (int g = 0; g < 4; ++g) for (int i = 0; i < 4; ++i) acc[f][g][i] = 0.f;
  float s[4] = {0.f, 0.f, 0.f, 0.f};
  #pragma unroll 2
  for (int kk = 0; kk < 256; kk += 32) {
    const int kc = kk + ((lane >> 4) << 3);
    short8v av[4], bv[4];
    #pragma unroll
    for (int f = 0; f < 4; ++f)
      av[f] = *(const short8v*)(A + (size_t)(ar + f * 16 + (lane & 15)) * DD + kc);
    #pragma unroll
    for (int g = 0; g < 4; ++g)
      bv[g] = *(const short8v*)(B + (size_t)(bc + g * 16 + (lane & 15)) * 256 + kc);
    if (gemv) {
      const float* mp = mcol + b * 256 + kc;
      f32x4 m0 = *(const f32x4*)mp, m1 = *(const f32x4*)(mp + 4);
      #pragma unroll
      for (int f = 0; f < 4; ++f) {
        #pragma unroll
        for (int q = 0; q < 4; ++q) {
          s[f] += b2f(av[f][q]) * m0[q];
          s[f] += b2f(av[f][4 + q]) * m1[q];
        }
      }
    }
    #pragma unroll
    for (int f = 0; f < 4; ++f)
      #pragma unroll
      for (int g = 0; g < 4; ++g)
        acc[f][g] = __builtin_amdgcn_mfma_f32_16x16x32_bf16(av[f], bv[g], acc[f][g], 0, 0, 0);
  }
  #pragma unroll
  for (int f = 0; f < 4; ++f)
    #pragma unroll
    for (int g = 0; g < 4; ++g)
      #pragma unroll
      for (int i = 0; i < 4; ++i) {
        int n = ar + f * 16 + ((lane >> 4) << 2) + i;
        int c = bc + g * 16 + (lane & 15);
        size_t idx = ((size_t)b * NTOK + n) * NCH + c;
        Z[idx] += acc[f][g][i];
      }
  if (gemv) {
    #pragma unroll
    for (int f = 0; f < 4; ++f) {
      float t = s[f];
      t += __shfl_xor(t, 16);
      t += __shfl_xor(t, 32);
      if ((lane >> 4) == 0) {
        int n = ar + f * 16 + (lane & 15);
        Z[((size_t)b * NTOK + n) * NCH + DD] += t;
      }
    }
  }
}

// ================= fallback (round-1 fp32 path, used if ws too small) =================
__global__ __launch_bounds__(256) void gram_kernel(const float* __restrict__ Z, float* __restrict__ G) {
  __shared__ float As[32][64];
  __shared__ float Bs[32][65];
  const int c0 = blockIdx.x * 64, k0 = blockIdx.y * 64, b = blockIdx.z;
  const int tid = threadIdx.x, tx = tid & 15, ty = tid >> 4;
  const float* Zb = Z + (size_t)b * NTOK * NCH;
  float acc[4][4] = {};
  for (int m0 = 0; m0 < NVAL; m0 += 32) {
    #pragma unroll
    for (int l = 0; l < 8; ++l) {
      int e = tid + l * 256, mm = e >> 6, kk = e & 63, m = m0 + mm;
      As[mm][kk] = (m < NVAL) ? Zb[(size_t)m * NCH + (k0 + kk)] : 0.f;
    }
    #pragma unroll
    for (int l = 0; l < 8; ++l) {
      int e = tid + l * 256, mm = e >> 6, cc = e & 63, m = m0 + mm, c = c0 + cc;
      Bs[mm][cc] = (m < NVAL && c < NCH) ? Zb[(size_t)m * NCH + c] : 0.f;
    }
    __syncthreads();
    #pragma unroll
    for (int mm = 0; mm < 32; ++mm) {
      float a[4], bb[4];
      #pragma unroll
      for (int i = 0; i < 4; ++i) a[i] = As[mm][ty * 4 + i];
      #pragma unroll
      for (int j = 0; j < 4; ++j) bb[j] = Bs[mm][tx * 4 + j];
      #pragma unroll
      for (int i = 0; i < 4; ++i)
        #pragma unroll
        for (int j = 0; j < 4; ++j) acc[i][j] += a[i] * bb[j];
    }
    __syncthreads();
  }
  float* Gb = G + (size_t)b * DD * NCH;
  #pragma unroll
  for (int i = 0; i < 4; ++i) {
    int k = k0 + ty * 4 + i;
    #pragma unroll
    for (int j = 0; j < 4; ++j) {
      int c = c0 + tx * 4 + j;
      if (c < NCH) Gb[(size_t)k * NCH + c] = acc[i][j];
    }
  }
}
__global__ __launch_bounds__(256) void pmul_kernel(const float* __restrict__ G, const float* __restrict__ allparam,
                                                   float* __restrict__ U, int layer, int j0, int JB) {
  __shared__ float As[64][33];
  __shared__ float Bs[64][33];
  const int c0 = blockIdx.x * 64, k0 = blockIdx.y * 64;
  const int b = blockIdx.z / JB, jj = blockIdx.z % JB, j = j0 + jj;
  const int tid = threadIdx.x, tx = tid & 15, ty = tid >> 4;
  const float* P = allparam + ((size_t)((layer * NH + j) * 2 + 0)) * DD * DD;
  const float* Gb = G + (size_t)b * DD * NCH;
  float acc[4][4] = {};
  for (int t0 = 0; t0 < DD; t0 += 32) {
    #pragma unroll
    for (int l = 0; l < 8; ++l) {
      int e = tid + l * 256, kk = e >> 5, tt = e & 31;
      As[kk][tt] = Gb[(size_t)(k0 + kk) * NCH + (t0 + tt)];
    }
    #pragma unroll
    for (int l = 0; l < 8; ++l) {
      int e = tid + l * 256, cc = e >> 5, tt = e & 31, c = c0 + cc;
      Bs[cc][tt] = (c < DD) ? P[(size_t)c * DD + (t0 + tt)] : 0.f;
    }
    __syncthreads();
    #pragma unroll
    for (int tt = 0; tt < 32; ++tt) {
      float a[4], bb[4];
      #pragma unroll
      for (int i = 0; i < 4; ++i) a[i] = As[ty * 4 + i][tt];
      #pragma unroll
      for (int j2 = 0; j2 < 4; ++j2) bb[j2] = Bs[tx * 4 + j2][tt];
      #pragma unroll
      for (int i = 0; i < 4; ++i)
        #pragma unroll
        for (int j2 = 0; j2 < 4; ++j2) acc[i][j2] += a[i] * bb[j2];
    }
    __syncthreads();
  }
  float* Us = U + ((size_t)(b * JB + jj)) * DD * NCH;
  #pragma unroll
  for (int i = 0; i < 4; ++i) {
    int k = k0 + ty * 4 + i;
    #pragma unroll
    for (int j2 = 0; j2 < 4; ++j2) {
      int c = c0 + tx * 4 + j2;
      if (c < DD)       Us[(size_t)k * NCH + c] = acc[i][j2];
      else if (c == DD) Us[(size_t)k * NCH + c] = Gb[(size_t)k * NCH + DD];
    }
  }
}
__global__ __launch_bounds__(256) void qmul_kernel(const float* __restrict__ U, const float* __restrict__ allparam,
                                                   float* __restrict__ M, int layer, int j0, int jcount, int JB,
                                                   int accumulate) {
  __shared__ float As[64][33];
  __shared__ float Bs[32][65];
  const int c0 = blockIdx.x * 64, k0 = blockIdx.y * 64, b = blockIdx.z;
  const int tid = threadIdx.x, tx = tid & 15, ty = tid >> 4;
  const float invN = 1.0f / (float)NVAL;
  float acc[4][4] = {};
  for (int jj = 0; jj < jcount; ++jj) {
    const float* Q = allparam + ((size_t)((layer * NH + (j0 + jj)) * 2 + 1)) * DD * DD;
    const float* Ub = U + ((size_t)(b * JB + jj)) * DD * NCH;
    for (int t0 = 0; t0 < DD; t0 += 32) {
      #pragma unroll
      for (int l = 0; l < 8; ++l) {
        int e = tid + l * 256, kk = e >> 5, tt = e & 31;
        As[kk][tt] = Q[(size_t)(k0 + kk) * DD + (t0 + tt)];
      }
      #pragma unroll
      for (int l = 0; l < 8; ++l) {
        int e = tid + l * 256, tt = e >> 6, cc = e & 63, c = c0 + cc;
        Bs[tt][cc] = (c < NCH) ? Ub[(size_t)(t0 + tt) * NCH + c] : 0.f;
      }
      __syncthreads();
      #pragma unroll
      for (int tt = 0; tt < 32; ++tt) {
        float a[4], bb[4];
        #pragma unroll
        for (int i = 0; i < 4; ++i) a[i] = As[ty * 4 + i][tt];
        #pragma unroll
        for (int j2 = 0; j2 < 4; ++j2) bb[j2] = Bs[tt][tx * 4 + j2];
        #pragma unroll
        for (int i = 0; i < 4; ++i)
          #pragma unroll
          for (int j2 = 0; j2 < 4; ++j2) acc[i][j2] += a[i] * bb[j2];
      }
      __syncthreads();
    }
  }
  #pragma unroll
  for (int i = 0; i < 4; ++i) {
    int k = k0 + ty * 4 + i;
    #pragma unroll
    for (int j2 = 0; j2 < 4; ++j2) {
      int c = c0 + tx * 4 + j2;
      if (c < NCH) {
        size_t idx = ((size_t)b * DD + k) * NCH + c;
        float v = invN * acc[i][j2];
        M[idx] = accumulate ? (M[idx] + v) : v;
      }
    }
  }
}
__global__ __launch_bounds__(256) void apply_kernel(float* __restrict__ Z, const float* __restrict__ M) {
  __shared__ float Zs[8][256];
  const int b = blockIdx.y, n0 = blockIdx.x * 8;
  float* Zb = Z + (size_t)b * NTOK * NCH;
  const float* Mb = M + (size_t)b * DD * NCH;
  const int tid = threadIdx.x;
  #pragma unroll
  for (int l = 0; l < 8; ++l) {
    int e = tid + l * 256, r = e >> 8, k = e & 255;
    Zs[r][k] = Zb[(size_t)(n0 + r) * NCH + k];
  }
  __syncthreads();
  const int r = tid >> 5, cbase = tid & 31;
  float acc[9] = {};
  #pragma unroll 4
  for (int k = 0; k < 256; ++k) {
    float z = Zs[r][k];
    const float* Mrow = Mb + (size_t)k * NCH;
    #pragma unroll
    for (int ii = 0; ii < 8; ++ii) acc[ii] += z * Mrow[cbase + ii * 32];
    if (cbase == 0) acc[8] += z * Mrow[256];
  }
  #pragma unroll
  for (int ii = 0; ii < 8; ++ii)
    Zb[(size_t)(n0 + r) * NCH + cbase + ii * 32] += acc[ii];
  if (cbase == 0) Zb[(size_t)(n0 + r) * NCH + 256] += acc[8];
}

// =====================================================================================
extern "C" void kernel_launch(void* const* d_in, const int* in_sizes, int n_in,
                              void* d_out, int out_size, void* d_ws, size_t ws_size,
                              hipStream_t stream) {
  const float* Zin      = (const float*)d_in[0];
  const float* allparam = (const float*)d_in[1];
  float* Z = (float*)d_out;
  const size_t zbytes = (size_t)NB * NTOK * NCH * sizeof(float);

  // ws layout (bytes)
  const size_t o_zxbf = 0;                         // bf16 [8][2048][256]  8,388,608
  const size_t o_zxt  = o_zxbf + 8388608;          // bf16 [8][256][2048]  8,388,608
  const size_t o_gacc = o_zxt  + 8388608;          // f32  [8][8][256][256] 16,777,216 (aliased as Macc[4][8])
  const size_t o_gbf  = o_gacc + 16777216;         // bf16 [8][256][256]   1,048,576
  const size_t o_vt   = o_gbf  + 1048576;          // bf16 [8][8][256][256] 8,388,608
  const size_t o_mt   = o_vt   + 8388608;          // bf16 [8][256][256]   1,048,576
  const size_t o_pbf  = o_mt   + 1048576;          // bf16 [4][8][256][256] 4,194,304
  const size_t o_qbf  = o_pbf  + 4194304;          // bf16                 4,194,304
  const size_t o_qsum = o_qbf  + 4194304;          // f32  [4][256][256]   1,048,576
  const size_t o_gcol = o_qsum + 1048576;          // f32  [8][256]        8,192
  const size_t o_mcol = o_gcol + 8192;             // f32  [8][256]        8,192
  const size_t NEED   = o_mcol + 8192;

  if (ws_size >= NEED) {
    char* wsb = (char*)d_ws;
    short* Zxbf = (short*)(wsb + o_zxbf);
    short* Zxt  = (short*)(wsb + o_zxt);
    float* Gacc = (float*)(wsb + o_gacc);
    float* Macc = Gacc;                               // alias (dead after gconv)
    short* Gbf  = (short*)(wsb + o_gbf);
    short* Vt   = (short*)(wsb + o_vt);
    short* Mt   = (short*)(wsb + o_mt);
    short* Pbf  = (short*)(wsb + o_pbf);
    short* Qbf  = (short*)(wsb + o_qbf);
    float* QsumT= (float*)(wsb + o_qsum);
    float* gcol = (float*)(wsb + o_gcol);
    float* mcol = (float*)(wsb + o_mcol);

    hipMemcpyAsync(Z, Zin, zbytes, hipMemcpyDeviceToDevice, stream);
    hipMemsetAsync(gcol, 0, 8192, stream);
    k_prep_pq<<<dim3(2048), dim3(256), 0, stream>>>(allparam, Pbf, Qbf);
    k_qsumt<<<dim3(16, 4), dim3(256), 0, stream>>>(allparam, QsumT);

    for (int layer = 0; layer < NL; ++layer) {
      k_transpose<<<dim3(4, 32, NB), dim3(256), 0, stream>>>(Z, Zxt, Zxbf, gcol);
      k_gram<<<dim3(4, 8, NB), dim3(256), 0, stream>>>(Zxt, Gacc);
      k_gconv<<<dim3(256), dim3(256), 0, stream>>>(Gacc, Gbf);
      k_pmul<<<dim3(4, 8, NB), dim3(256), 0, stream>>>(Gbf, Pbf, Vt, layer);
      k_qmul<<<dim3(4, 4, NB), dim3(256), 0, stream>>>(Qbf, Vt, Macc, layer);
      k_mconv<<<dim3(17, NB), dim3(256), 0, stream>>>(Macc, Mt, QsumT, gcol, mcol, layer);
      k_apply<<<dim3(2, 16, NB), dim3(256), 0, stream>>>(Z, Zxbf, Mt, mcol, gcol);
    }
    return;
  }

  // -------- fallback: round-1 fp32 path --------
  hipMemcpyAsync(Z, Zin, zbytes, hipMemcpyDeviceToDevice, stream);
  const size_t Gn = (size_t)NB * DD * NCH;
  float* ws   = (float*)d_ws;
  float* Gbuf = ws;
  float* Mbuf = ws + Gn;
  float* Ubuf = ws + 2 * Gn;
  const int JB = (ws_size >= (size_t)(2 + 8) * Gn * sizeof(float)) ? 8 : 1;
  dim3 blk(256);
  for (int layer = 0; layer < NL; ++layer) {
    gram_kernel<<<dim3(5, 4, NB), blk, 0, stream>>>(Z, Gbuf);
    for (int j0 = 0; j0 < NH; j0 += JB) {
      pmul_kernel<<<dim3(5, 4, NB * JB), blk, 0, stream>>>(Gbuf, allparam, Ubuf, layer, j0, JB);
      qmul_kernel<<<dim3(5, 4, NB), blk, 0, stream>>>(Ubuf, allparam, Mbuf, layer, j0, JB, JB,
                                                      (j0 == 0) ? 0 : 1);
    }
    apply_kernel<<<dim3(NTOK / 8, NB), blk, 0, stream>>>(Z, Mbuf);
  }
}